// Round 1
// baseline (390.767 us; speedup 1.0000x reference)
//
#include <hip/hip_runtime.h>

#define B_ 32
#define S_ 2048
#define H_ 1024
#define NCHUNK 128                // chunks per batch row; one wave per (b, chunk)
#define ROWS (S_ / NCHUNK)        // 16 s-rows per wave

typedef __attribute__((ext_vector_type(4))) float f32x4;

// ---------------------------------------------------------------------------
// Kernel 1: vpart[ks][b][h] = sum_{k in ks-chunk} h_t[b,k] * W[k,h]
// Split-K (4 chunks of 256) to break the serial FMA chain. (unchanged)
__global__ __launch_bounds__(256) void k_v(const float* __restrict__ h_t,
                                           const float* __restrict__ W,
                                           float* __restrict__ vpart) {
    __shared__ float sh[256];
    int b = blockIdx.x, hb = blockIdx.y, ks = blockIdx.z;
    int h = hb * 256 + threadIdx.x;
    sh[threadIdx.x] = h_t[b * H_ + ks * 256 + threadIdx.x];
    __syncthreads();
    const float* wp = W + (size_t)(ks * 256) * H_ + h;
    float a0 = 0.f, a1 = 0.f, a2 = 0.f, a3 = 0.f;
    #pragma unroll 4
    for (int k = 0; k < 256; k += 4) {
        a0 = fmaf(sh[k],     wp[(size_t)k * H_],        a0);
        a1 = fmaf(sh[k + 1], wp[(size_t)(k + 1) * H_],  a1);
        a2 = fmaf(sh[k + 2], wp[(size_t)(k + 2) * H_],  a2);
        a3 = fmaf(sh[k + 3], wp[(size_t)(k + 3) * H_],  a3);
    }
    vpart[((size_t)ks * B_ + b) * H_ + h] = (a0 + a1) + (a2 + a3);
}

// ---------------------------------------------------------------------------
// Kernel 2: fused flash pass. One wave per (b, chunk).
// CHANGES vs prev: depth-2 row prefetch (8 KB in flight/wave instead of 4 KB),
// plain loads instead of nontemporal (rule out gfx950 nt-load pathology),
// dot-product chain split into 4 accumulators (chain 16 -> 4 deep).
__global__ __launch_bounds__(256, 4) void k_flash(const float* __restrict__ cntx,
                                                  const float* __restrict__ vpart,
                                                  float* __restrict__ partO,
                                                  float* __restrict__ stats) {
    int gw   = blockIdx.x * 4 + (threadIdx.x >> 6);   // wave id in [0, B_*NCHUNK)
    int lane = threadIdx.x & 63;
    int b    = gw >> 7;                                // NCHUNK = 128
    int ch   = gw & (NCHUNK - 1);

    // v fragment: vv[q] covers h = q*256 + lane*4 .. +3; sum 4 k-split partials
    f32x4 vv[4];
    #pragma unroll
    for (int q = 0; q < 4; ++q) {
        f32x4 t0 = *(const f32x4*)(vpart + ((size_t)0 * B_ + b) * H_ + q * 256 + lane * 4);
        f32x4 t1 = *(const f32x4*)(vpart + ((size_t)1 * B_ + b) * H_ + q * 256 + lane * 4);
        f32x4 t2 = *(const f32x4*)(vpart + ((size_t)2 * B_ + b) * H_ + q * 256 + lane * 4);
        f32x4 t3 = *(const f32x4*)(vpart + ((size_t)3 * B_ + b) * H_ + q * 256 + lane * 4);
        vv[q] = (t0 + t1) + (t2 + t3);
    }

    const float* rp = cntx + ((size_t)b * S_ + (size_t)ch * ROWS) * H_ + lane * 4;
    f32x4 acc[4];
    #pragma unroll
    for (int q = 0; q < 4; ++q) acc[q] = (f32x4){0.f, 0.f, 0.f, 0.f};
    float m = -1e30f, l = 0.f;

    // depth-2 prefetch pipeline: cn = row s, cn2 = row s+1
    f32x4 cn[4], cn2[4];
    #pragma unroll
    for (int q = 0; q < 4; ++q) cn[q]  = *(const f32x4*)(rp + q * 256);
    #pragma unroll
    for (int q = 0; q < 4; ++q) cn2[q] = *(const f32x4*)(rp + H_ + q * 256);
    const float* pf = rp + 2 * (size_t)H_;            // next row to issue

    for (int s = 0; s < ROWS; ++s) {
        f32x4 c[4];
        #pragma unroll
        for (int q = 0; q < 4; ++q) { c[q] = cn[q]; cn[q] = cn2[q]; }
        if (s + 2 < ROWS) {
            #pragma unroll
            for (int q = 0; q < 4; ++q)
                cn2[q] = *(const f32x4*)(pf + q * 256);
            pf += H_;
        }
        // dot(c, vv): 4 parallel chains instead of 1x16 chain
        float d0 = 0.f, d1 = 0.f, d2 = 0.f, d3 = 0.f;
        #pragma unroll
        for (int q = 0; q < 4; ++q) {
            d0 = fmaf(c[q][0], vv[q][0], d0);
            d1 = fmaf(c[q][1], vv[q][1], d1);
            d2 = fmaf(c[q][2], vv[q][2], d2);
            d3 = fmaf(c[q][3], vv[q][3], d3);
        }
        float d = (d0 + d1) + (d2 + d3);
        #pragma unroll
        for (int off = 32; off; off >>= 1) d += __shfl_xor(d, off);

        float mn = fmaxf(m, d);
        float al = __expf(m - mn);     // first iter: exp(-huge) = 0 kills stale acc
        float p  = __expf(d - mn);
        l = fmaf(l, al, p);
        #pragma unroll
        for (int q = 0; q < 4; ++q)
            #pragma unroll
            for (int j = 0; j < 4; ++j)
                acc[q][j] = fmaf(acc[q][j], al, p * c[q][j]);
        m = mn;
    }

    float* po = partO + (size_t)gw * H_;
    #pragma unroll
    for (int q = 0; q < 4; ++q) *(f32x4*)(po + q * 256 + lane * 4) = acc[q];
    if (lane == 0) { stats[gw * 2] = m; stats[gw * 2 + 1] = l; }
}

// ---------------------------------------------------------------------------
// Kernel 3: combine 128 chunk partials with their (m,l) stats + final blend.
// grid (B, H/256), block 256. (unchanged)
__global__ __launch_bounds__(256) void k_combine(const float* __restrict__ h_t,
                                                 const float* __restrict__ partO,
                                                 const float* __restrict__ stats,
                                                 const float* __restrict__ alpha,
                                                 const float* __restrict__ beta,
                                                 float* __restrict__ out) {
    int b = blockIdx.x, hb = blockIdx.y;
    int t = threadIdx.x;
    int wid = t >> 6;
    __shared__ float sw[NCHUNK];
    __shared__ float redm[2];
    __shared__ float reds[2];
    float mg = 0.f, lg = 0.f;
    if (t < NCHUNK) {                          // waves 0 and 1 exactly
        mg = stats[(b * NCHUNK + t) * 2];
        lg = stats[(b * NCHUNK + t) * 2 + 1];
        float M = mg;
        #pragma unroll
        for (int off = 32; off; off >>= 1) M = fmaxf(M, __shfl_xor(M, off));
        if ((t & 63) == 0) redm[wid] = M;
    }
    __syncthreads();
    float M = fmaxf(redm[0], redm[1]);
    if (t < NCHUNK) {
        float w = __expf(mg - M);
        sw[t] = w;
        float d = w * lg;
        #pragma unroll
        for (int off = 32; off; off >>= 1) d += __shfl_xor(d, off);
        if ((t & 63) == 0) reds[wid] = d;
    }
    __syncthreads();
    float den = reds[0] + reds[1];
    int h = hb * 256 + t;
    float sum = 0.f;
    #pragma unroll 8
    for (int g = 0; g < NCHUNK; ++g)
        sum = fmaf(sw[g], partO[(size_t)(b * NCHUNK + g) * H_ + h], sum);
    out[b * H_ + h] = fmaf(alpha[0], h_t[b * H_ + h], beta[0] * (sum / den));
}

// ---------------------------------------------------------------------------
extern "C" void kernel_launch(void* const* d_in, const int* in_sizes, int n_in,
                              void* d_out, int out_size, void* d_ws, size_t ws_size,
                              hipStream_t stream) {
    const float* h_t   = (const float*)d_in[0];
    const float* cntx  = (const float*)d_in[1];
    const float* W     = (const float*)d_in[2];
    const float* alpha = (const float*)d_in[3];
    const float* beta  = (const float*)d_in[4];
    float* out = (float*)d_out;

    float* vpart = (float*)d_ws;                        // 4*B_*H_      = 131072 floats
    float* partO = vpart + 4 * B_ * H_;                 // B_*NCHUNK*H_ = 4194304 floats
    float* stats = partO + (size_t)B_ * NCHUNK * H_;    // B_*NCHUNK*2  = 8192 floats

    k_v<<<dim3(B_, H_ / 256, 4), 256, 0, stream>>>(h_t, W, vpart);
    k_flash<<<dim3(B_ * NCHUNK / 4), 256, 0, stream>>>(cntx, vpart, partO, stats);
    k_combine<<<dim3(B_, H_ / 256), 256, 0, stream>>>(h_t, partO, stats, alpha, beta, out);
}

// Round 2
// 372.253 us; speedup vs baseline: 1.0497x; 1.0497x over previous
//
#include <hip/hip_runtime.h>

#define B_ 32
#define S_ 2048
#define H_ 1024
#define NCHUNK 128                // chunks per batch row; one wave per (b, chunk)
#define ROWS (S_ / NCHUNK)        // 16 s-rows per wave

typedef __attribute__((ext_vector_type(4))) float f32x4;

// ---------------------------------------------------------------------------
// Kernel 1: vpart[ks][b][h] = sum_{k in ks-chunk} h_t[b,k] * W[k,h]
// Split-K (4 chunks of 256) to break the serial FMA chain. (unchanged)
__global__ __launch_bounds__(256) void k_v(const float* __restrict__ h_t,
                                           const float* __restrict__ W,
                                           float* __restrict__ vpart) {
    __shared__ float sh[256];
    int b = blockIdx.x, hb = blockIdx.y, ks = blockIdx.z;
    int h = hb * 256 + threadIdx.x;
    sh[threadIdx.x] = h_t[b * H_ + ks * 256 + threadIdx.x];
    __syncthreads();
    const float* wp = W + (size_t)(ks * 256) * H_ + h;
    float a0 = 0.f, a1 = 0.f, a2 = 0.f, a3 = 0.f;
    #pragma unroll 4
    for (int k = 0; k < 256; k += 4) {
        a0 = fmaf(sh[k],     wp[(size_t)k * H_],        a0);
        a1 = fmaf(sh[k + 1], wp[(size_t)(k + 1) * H_],  a1);
        a2 = fmaf(sh[k + 2], wp[(size_t)(k + 2) * H_],  a2);
        a3 = fmaf(sh[k + 3], wp[(size_t)(k + 3) * H_],  a3);
    }
    vpart[((size_t)ks * B_ + b) * H_ + h] = (a0 + a1) + (a2 + a3);
}

// ---------------------------------------------------------------------------
// Kernel 2: fused flash pass. One wave per (b, chunk).
// CHANGES vs round 1: nontemporal loads RESTORED for the cntx stream (268 MB
// pure stream > L3; plain loads polluted L2/L3 and cost +23 us). Depth-2 row
// prefetch and 4-way split dot chains kept.
__global__ __launch_bounds__(256, 4) void k_flash(const float* __restrict__ cntx,
                                                  const float* __restrict__ vpart,
                                                  float* __restrict__ partO,
                                                  float* __restrict__ stats) {
    int gw   = blockIdx.x * 4 + (threadIdx.x >> 6);   // wave id in [0, B_*NCHUNK)
    int lane = threadIdx.x & 63;
    int b    = gw >> 7;                                // NCHUNK = 128
    int ch   = gw & (NCHUNK - 1);

    // v fragment: vv[q] covers h = q*256 + lane*4 .. +3; sum 4 k-split partials
    f32x4 vv[4];
    #pragma unroll
    for (int q = 0; q < 4; ++q) {
        f32x4 t0 = *(const f32x4*)(vpart + ((size_t)0 * B_ + b) * H_ + q * 256 + lane * 4);
        f32x4 t1 = *(const f32x4*)(vpart + ((size_t)1 * B_ + b) * H_ + q * 256 + lane * 4);
        f32x4 t2 = *(const f32x4*)(vpart + ((size_t)2 * B_ + b) * H_ + q * 256 + lane * 4);
        f32x4 t3 = *(const f32x4*)(vpart + ((size_t)3 * B_ + b) * H_ + q * 256 + lane * 4);
        vv[q] = (t0 + t1) + (t2 + t3);
    }

    const float* rp = cntx + ((size_t)b * S_ + (size_t)ch * ROWS) * H_ + lane * 4;
    f32x4 acc[4];
    #pragma unroll
    for (int q = 0; q < 4; ++q) acc[q] = (f32x4){0.f, 0.f, 0.f, 0.f};
    float m = -1e30f, l = 0.f;

    // depth-2 prefetch pipeline: cn = row s, cn2 = row s+1
    f32x4 cn[4], cn2[4];
    #pragma unroll
    for (int q = 0; q < 4; ++q)
        cn[q]  = __builtin_nontemporal_load((const f32x4*)(rp + q * 256));
    #pragma unroll
    for (int q = 0; q < 4; ++q)
        cn2[q] = __builtin_nontemporal_load((const f32x4*)(rp + H_ + q * 256));
    const float* pf = rp + 2 * (size_t)H_;            // next row to issue

    for (int s = 0; s < ROWS; ++s) {
        f32x4 c[4];
        #pragma unroll
        for (int q = 0; q < 4; ++q) { c[q] = cn[q]; cn[q] = cn2[q]; }
        if (s + 2 < ROWS) {
            #pragma unroll
            for (int q = 0; q < 4; ++q)
                cn2[q] = __builtin_nontemporal_load((const f32x4*)(pf + q * 256));
            pf += H_;
        }
        // dot(c, vv): 4 parallel chains instead of 1x16 chain
        float d0 = 0.f, d1 = 0.f, d2 = 0.f, d3 = 0.f;
        #pragma unroll
        for (int q = 0; q < 4; ++q) {
            d0 = fmaf(c[q][0], vv[q][0], d0);
            d1 = fmaf(c[q][1], vv[q][1], d1);
            d2 = fmaf(c[q][2], vv[q][2], d2);
            d3 = fmaf(c[q][3], vv[q][3], d3);
        }
        float d = (d0 + d1) + (d2 + d3);
        #pragma unroll
        for (int off = 32; off; off >>= 1) d += __shfl_xor(d, off);

        float mn = fmaxf(m, d);
        float al = __expf(m - mn);     // first iter: exp(-huge) = 0 kills stale acc
        float p  = __expf(d - mn);
        l = fmaf(l, al, p);
        #pragma unroll
        for (int q = 0; q < 4; ++q)
            #pragma unroll
            for (int j = 0; j < 4; ++j)
                acc[q][j] = fmaf(acc[q][j], al, p * c[q][j]);
        m = mn;
    }

    float* po = partO + (size_t)gw * H_;
    #pragma unroll
    for (int q = 0; q < 4; ++q) *(f32x4*)(po + q * 256 + lane * 4) = acc[q];
    if (lane == 0) { stats[gw * 2] = m; stats[gw * 2 + 1] = l; }
}

// ---------------------------------------------------------------------------
// Kernel 3: combine 128 chunk partials with their (m,l) stats + final blend.
// grid (B, H/256), block 256. (unchanged; partO reads want to hit L3 -> keep
// plain cached loads here and plain writes in k_flash)
__global__ __launch_bounds__(256) void k_combine(const float* __restrict__ h_t,
                                                 const float* __restrict__ partO,
                                                 const float* __restrict__ stats,
                                                 const float* __restrict__ alpha,
                                                 const float* __restrict__ beta,
                                                 float* __restrict__ out) {
    int b = blockIdx.x, hb = blockIdx.y;
    int t = threadIdx.x;
    int wid = t >> 6;
    __shared__ float sw[NCHUNK];
    __shared__ float redm[2];
    __shared__ float reds[2];
    float mg = 0.f, lg = 0.f;
    if (t < NCHUNK) {                          // waves 0 and 1 exactly
        mg = stats[(b * NCHUNK + t) * 2];
        lg = stats[(b * NCHUNK + t) * 2 + 1];
        float M = mg;
        #pragma unroll
        for (int off = 32; off; off >>= 1) M = fmaxf(M, __shfl_xor(M, off));
        if ((t & 63) == 0) redm[wid] = M;
    }
    __syncthreads();
    float M = fmaxf(redm[0], redm[1]);
    if (t < NCHUNK) {
        float w = __expf(mg - M);
        sw[t] = w;
        float d = w * lg;
        #pragma unroll
        for (int off = 32; off; off >>= 1) d += __shfl_xor(d, off);
        if ((t & 63) == 0) reds[wid] = d;
    }
    __syncthreads();
    float den = reds[0] + reds[1];
    int h = hb * 256 + t;
    float sum = 0.f;
    #pragma unroll 8
    for (int g = 0; g < NCHUNK; ++g)
        sum = fmaf(sw[g], partO[(size_t)(b * NCHUNK + g) * H_ + h], sum);
    out[b * H_ + h] = fmaf(alpha[0], h_t[b * H_ + h], beta[0] * (sum / den));
}

// ---------------------------------------------------------------------------
extern "C" void kernel_launch(void* const* d_in, const int* in_sizes, int n_in,
                              void* d_out, int out_size, void* d_ws, size_t ws_size,
                              hipStream_t stream) {
    const float* h_t   = (const float*)d_in[0];
    const float* cntx  = (const float*)d_in[1];
    const float* W     = (const float*)d_in[2];
    const float* alpha = (const float*)d_in[3];
    const float* beta  = (const float*)d_in[4];
    float* out = (float*)d_out;

    float* vpart = (float*)d_ws;                        // 4*B_*H_      = 131072 floats
    float* partO = vpart + 4 * B_ * H_;                 // B_*NCHUNK*H_ = 4194304 floats
    float* stats = partO + (size_t)B_ * NCHUNK * H_;    // B_*NCHUNK*2  = 8192 floats

    k_v<<<dim3(B_, H_ / 256, 4), 256, 0, stream>>>(h_t, W, vpart);
    k_flash<<<dim3(B_ * NCHUNK / 4), 256, 0, stream>>>(cntx, vpart, partO, stats);
    k_combine<<<dim3(B_, H_ / 256), 256, 0, stream>>>(h_t, partO, stats, alpha, beta, out);
}